// Round 7
// baseline (540.672 us; speedup 1.0000x reference)
//
#include <hip/hip_runtime.h>
#include <cstdint>

#define EMB   1024
#define HEADS 16
#define HDIM  64
#define DFF   4096
#define TLEN  2048
#define BATCH 4
#define SEQB  8192   // BATCH*TLEN token rows
#define EPSLN 1e-5f

typedef __attribute__((ext_vector_type(8))) short bf16x8;
typedef __attribute__((ext_vector_type(4))) float f32x4;

#define MFMA16(a, b, c) __builtin_amdgcn_mfma_f32_16x16x32_bf16((a), (b), (c), 0, 0, 0)

__device__ __forceinline__ unsigned short f2bf(float f) {
  unsigned int u = __float_as_uint(f);
  u += 0x7fffu + ((u >> 16) & 1u);   // round-to-nearest-even
  return (unsigned short)(u >> 16);
}

// tanh-form GELU: 0.5x(1+tanh(.79788456(x+.044715x^3))) = x*t/(t+1),
// t = exp2(2.885390082*(.79788456x+.035677408x^3)); |err| ~3e-4, cheap (no erf).
__device__ __forceinline__ float gelu_f(float x) {
  float x2 = x * x;
  float inner = x * (0.79788456f + 0.035677408f * x2);
  float t = exp2f(2.885390082f * inner);
  return x * t / (t + 1.0f);
}

// ---------------------------------------------------------------- prep: fused one-shot setup
// blocks [0,12288): weight fp32->bf16 cvt (wq,wk,wv -> packed wqkv; wo; l1; l2)
// blocks [12288,20480): LN1 row sums over x (row = bid-12288)
// blocks [20480,20492): pack3 qkv bias
// blocks [20492,20508): zero rs2/rq2 (LN2 accumulators fed by Wo epilogue atomics)
__global__ __launch_bounds__(256) void prep(const float* __restrict__ wq, const float* __restrict__ wk,
                                            const float* __restrict__ wv, const float* __restrict__ wom,
                                            const float* __restrict__ l1w, const float* __restrict__ l2w,
                                            unsigned short* __restrict__ wqkv, unsigned short* __restrict__ wo,
                                            unsigned short* __restrict__ l1, unsigned short* __restrict__ l2,
                                            const float* __restrict__ bq, const float* __restrict__ bk,
                                            const float* __restrict__ bv, float* __restrict__ bqkv,
                                            const float* __restrict__ X, float* __restrict__ rs,
                                            float* __restrict__ rq, float* __restrict__ rs2,
                                            float* __restrict__ rq2) {
  __shared__ float ss[4], sq[4];
  const int bid = blockIdx.x;
  const int tid = threadIdx.x;
  if (bid < 12288) {                       // ---- weight cvt (exact-range, no bounds check)
    const float* src;
    unsigned short* dst;
    int off;
    if (bid < 1024)      { src = wq;  dst = wqkv;               off = bid; }
    else if (bid < 2048) { src = wk;  dst = wqkv + (1 << 20);   off = bid - 1024; }
    else if (bid < 3072) { src = wv;  dst = wqkv + (2 << 20);   off = bid - 2048; }
    else if (bid < 4096) { src = wom; dst = wo;                 off = bid - 3072; }
    else if (bid < 8192) { src = l1w; dst = l1;                 off = bid - 4096; }
    else                 { src = l2w; dst = l2;                 off = bid - 8192; }
    const int i = off * 256 + tid;
    float4 v = ((const float4*)src)[i];
    ushort4 o;
    o.x = f2bf(v.x); o.y = f2bf(v.y); o.z = f2bf(v.z); o.w = f2bf(v.w);
    ((ushort4*)dst)[i] = o;
  } else if (bid < 20480) {                // ---- LN1 row reduce
    const int row = bid - 12288;
    float4 v = ((const float4*)(X + (long)row * EMB))[tid];
    float s = v.x + v.y + v.z + v.w;
    float q = v.x * v.x + v.y * v.y + v.z * v.z + v.w * v.w;
#pragma unroll
    for (int d = 1; d < 64; d <<= 1) { s += __shfl_xor(s, d); q += __shfl_xor(q, d); }
    const int wv_ = tid >> 6;
    if ((tid & 63) == 0) { ss[wv_] = s; sq[wv_] = q; }
    __syncthreads();
    if (tid == 0) {
      rs[row] = ss[0] + ss[1] + ss[2] + ss[3];
      rq[row] = sq[0] + sq[1] + sq[2] + sq[3];
    }
  } else if (bid < 20492) {                // ---- pack3 qkv bias
    const int i = (bid - 20480) * 256 + tid;  // 0..3071
    bqkv[i] = i < 1024 ? bq[i] : (i < 2048 ? bk[i - 1024] : bv[i - 2048]);
  } else {                                 // ---- zero rs2/rq2 (4096 float4 total)
    const int i = (bid - 20492) * 256 + tid;  // 0..4095
    if (i < 2048) ((float4*)rs2)[i] = (float4){0.f, 0.f, 0.f, 0.f};
    else          ((float4*)rq2)[i - 2048] = (float4){0.f, 0.f, 0.f, 0.f};
  }
}

// ---------------------------------------------------------------- LN pass 2: global var
__global__ __launch_bounds__(256) void finalize_stats(const float* __restrict__ rs,
                                                      const float* __restrict__ rq,
                                                      float* __restrict__ stats) {
  const int tid = threadIdx.x;
  float s = 0.f, q = 0.f;
  for (int i = tid; i < SEQB; i += 256) { s += rs[i]; q += rq[i]; }
#pragma unroll
  for (int d = 1; d < 64; d <<= 1) { s += __shfl_xor(s, d); q += __shfl_xor(q, d); }
  __shared__ float ss[4], sq[4];
  const int wv = tid >> 6;
  if ((tid & 63) == 0) { ss[wv] = s; sq[wv] = q; }
  __syncthreads();
  if (tid == 0) {
    double n = (double)SEQB * (double)EMB;
    double mean = (double)(ss[0] + ss[1] + ss[2] + ss[3]) / n;
    double var = (double)(sq[0] + sq[1] + sq[2] + sq[3]) / n - mean * mean;
    stats[0] = (float)(1.0 / var);
  }
}

// ---------------------------------------------------------------- LN apply + cast bf16
__global__ __launch_bounds__(256) void ln_apply(const float* __restrict__ X,
                                                const float* __restrict__ rs,
                                                const float* __restrict__ stats,
                                                const float* __restrict__ scale,
                                                const float* __restrict__ shift,
                                                unsigned short* __restrict__ H) {
  const long i = (long)blockIdx.x * 256 + threadIdx.x;  // float4 index
  const long idx = i * 4;
  const int row = (int)(idx >> 10);
  const int c = (int)(idx & 1023);
  const float mean = rs[row] * (1.0f / EMB);
  const float iv = stats[0];
  float4 x = ((const float4*)X)[i];
  float4 sc = *(const float4*)(scale + c);
  float4 sh = *(const float4*)(shift + c);
  ushort4 o;
  o.x = f2bf(((x.x - mean) * iv + EPSLN) * sc.x + sh.x);
  o.y = f2bf(((x.y - mean) * iv + EPSLN) * sc.y + sh.y);
  o.z = f2bf(((x.z - mean) * iv + EPSLN) * sc.z + sh.z);
  o.w = f2bf(((x.w - mean) * iv + EPSLN) * sc.w + sh.w);
  ((ushort4*)H)[i] = o;
}

// ---------------------------------------------------------------- GEMM: C = A (bf16 [M][K]) x W^T (bf16 [N][K]) + bias
// Harness-proven 128x128 structure (552->540 us configs): 256 thr, 32 KiB LDS,
// XOR-swizzled (SQ_LDS_BANK_CONFLICT=0 measured), T1 XCD remap. K-loop untouched.
// EPI 0: bf16 ; EPI 1: fp32 (+residual) ; EPI 2: tanh-GELU -> bf16
// EPI 3: fp32 (+residual) + per-row sum/sumsq atomics into kout/vout (as float*)
//        -- fuses LN2's row_reduce into the Wo projection (WRITE_SIZE showed no
//        RMW inflation here, so only the extra 32MB read pass is worth removing).
// EPI 4: fused QKV: seg=bn>>10 (block-uniform): 0 -> q, 1 -> k, 2 -> v transposed [b*1024+d][t]
template <int EPI>
__global__ __launch_bounds__(256) void gemm_bt(const unsigned short* __restrict__ A,
                                               const unsigned short* __restrict__ W,
                                               const float* __restrict__ bias,
                                               const float* __restrict__ resid,
                                               void* __restrict__ Cout,
                                               unsigned short* __restrict__ kout,
                                               unsigned short* __restrict__ vout,
                                               int M, int N, int K) {
  __shared__ unsigned short sA[128 * 64];
  __shared__ unsigned short sB[128 * 64];
  const int tid = threadIdx.x;
  const int lane = tid & 63;
  const int wave = tid >> 6;
  const int wm = (wave >> 1) * 64, wn = (wave & 1) * 64;
  const int col = lane & 15, quad = lane >> 4;
  const int cx = (col & 7) * 8;            // read-side xor key (halves)

  // T1: XCD-aware bijective block remap (8 XCDs on MI355X)
  const int gx = (int)gridDim.x, gy = (int)gridDim.y;
  const int nwg = gx * gy;
  int bid = (int)blockIdx.y * gx + (int)blockIdx.x;
  if ((nwg & 7) == 0) bid = (bid & 7) * (nwg >> 3) + (bid >> 3);
  const int bx = bid % gx;
  const int by = bid / gx;
  const long bm = (long)by * 128, bn = (long)bx * 128;

  f32x4 acc[4][4];
#pragma unroll
  for (int i = 0; i < 4; ++i)
#pragma unroll
    for (int j = 0; j < 4; ++j) acc[i][j] = (f32x4){0.f, 0.f, 0.f, 0.f};

  const int r0 = tid >> 3;
  const int kg = (tid & 7) * 8;
  const int rx = (r0 & 7) * 8;             // staging-side xor key (halves)
  const int kgx = kg ^ rx;                 // swizzled source column chunk

  for (int k0 = 0; k0 < K; k0 += 64) {
#pragma unroll
    for (int it = 0; it < 4; ++it) {
      const int r = it * 32 + r0;
      const unsigned short* ga = A + (bm + r) * K + k0 + kgx;
      const unsigned short* gb = W + (bn + r) * K + k0 + kgx;
      __builtin_amdgcn_global_load_lds((const __attribute__((address_space(1))) void*)ga,
                                       (__attribute__((address_space(3))) void*)&sA[r * 64 + kg],
                                       16, 0, 0);
      __builtin_amdgcn_global_load_lds((const __attribute__((address_space(1))) void*)gb,
                                       (__attribute__((address_space(3))) void*)&sB[r * 64 + kg],
                                       16, 0, 0);
    }
    __syncthreads();
#pragma unroll
    for (int ks = 0; ks < 2; ++ks) {
      const int off = (ks * 32 + quad * 8) ^ cx;
      bf16x8 af[4], bfr[4];
#pragma unroll
      for (int mt = 0; mt < 4; ++mt)
        af[mt] = *(const bf16x8*)&sA[(wm + mt * 16 + col) * 64 + off];
#pragma unroll
      for (int nt = 0; nt < 4; ++nt)
        bfr[nt] = *(const bf16x8*)&sB[(wn + nt * 16 + col) * 64 + off];
#pragma unroll
      for (int mt = 0; mt < 4; ++mt)
#pragma unroll
        for (int nt = 0; nt < 4; ++nt) acc[mt][nt] = MFMA16(af[mt], bfr[nt], acc[mt][nt]);
    }
    __syncthreads();
  }

#pragma unroll
  for (int mt = 0; mt < 4; ++mt) {
    const long row0 = bm + wm + mt * 16 + quad * 4;
    if (EPI == 3) {
      float s4[4] = {0.f, 0.f, 0.f, 0.f}, q4[4] = {0.f, 0.f, 0.f, 0.f};
#pragma unroll
      for (int nt = 0; nt < 4; ++nt) {
        const long c = bn + wn + nt * 16 + col;
        const float bv = bias[c];
#pragma unroll
        for (int r = 0; r < 4; ++r) {
          const long row = row0 + r;
          const float v = acc[mt][nt][r] + bv + resid[row * N + c];
          ((float*)Cout)[row * N + c] = v;
          s4[r] += v;
          q4[r] += v * v;
        }
      }
#pragma unroll
      for (int r = 0; r < 4; ++r)
#pragma unroll
        for (int d = 1; d < 16; d <<= 1) {
          s4[r] += __shfl_xor(s4[r], d);
          q4[r] += __shfl_xor(q4[r], d);
        }
      if (col == 0) {
#pragma unroll
        for (int r = 0; r < 4; ++r) {
          atomicAdd((float*)kout + row0 + r, s4[r]);
          atomicAdd((float*)vout + row0 + r, q4[r]);
        }
      }
    } else {
#pragma unroll
      for (int nt = 0; nt < 4; ++nt) {
        const long c = bn + wn + nt * 16 + col;
        const float bv = bias[c];
        if (EPI == 4) {
          const int seg = (int)(bn >> 10);  // block-uniform
          if (seg == 2) {
            ushort4 o;
#pragma unroll
            for (int r = 0; r < 4; ++r) o[r] = f2bf(acc[mt][nt][r] + bv);
            const long bidx = row0 >> 11;
            const long t0 = row0 & 2047;
            *(ushort4*)(vout + (((bidx * 1024 + (c & 1023)) << 11) + t0)) = o;
          } else {
            unsigned short* dst = seg == 0 ? (unsigned short*)Cout : kout;
#pragma unroll
            for (int r = 0; r < 4; ++r)
              dst[(row0 + r) * 1024 + (c & 1023)] = f2bf(acc[mt][nt][r] + bv);
          }
        } else {
#pragma unroll
          for (int r = 0; r < 4; ++r) {
            const long row = row0 + r;
            float v = acc[mt][nt][r] + bv;
            if (EPI == 0) {
              ((unsigned short*)Cout)[row * N + c] = f2bf(v);
            } else if (EPI == 1) {
              ((float*)Cout)[row * N + c] = v + resid[row * N + c];
            } else {
              ((unsigned short*)Cout)[row * N + c] = f2bf(gelu_f(v));
            }
          }
        }
      }
    }
  }
}

// ---------------------------------------------------------------- causal flash attention v10
// r6-proven: global_load_lds staging, swizzled LDS, coalesced LDS-staged epilogue
// (WRITE_SIZE inflation fix, +12 us measured r5->r6).
#define PSTR 136
__global__ __launch_bounds__(512, 4) void attn10(const unsigned short* __restrict__ Qb,
                                                 const unsigned short* __restrict__ Kb,
                                                 const unsigned short* __restrict__ vT,
                                                 unsigned short* __restrict__ Ctx) {
  __shared__ unsigned short sK[128 * 64];   // [t_local][d] 16KB, xor-swizzled
  __shared__ unsigned short sV[64 * 128];   // [d][s_local] 16KB, xor-swizzled
  __shared__ unsigned short sP[8][16 * PSTR];
  const int bh = blockIdx.x;                   // b*16+h
  const int pair = blockIdx.y;                 // 0..7
  const int b = bh >> 4, h = bh & 15;
  const int tid = threadIdx.x, lane = tid & 63, w = tid >> 6;
  const int col = lane & 15, quad = lane >> 4;
  const int cx = (col & 7) * 8;                // read-side xor key
  const long bbase = (long)b * TLEN;
  const long hoff = (long)h * HDIM;
  const unsigned short* vbase = vT + (((long)b * 16 + h) * HDIM << 11);
  const float sc2 = 0.125f * 1.44269504088896340736f;  // (1/sqrt(64)) * log2(e)

  // staging decomposition (block-wide, 512 threads x 16B):
  const int krow = tid >> 3;          // K: 64 rows per round
  const int kcol = ((tid & 7) * 8) ^ ((krow & 7) * 8);   // swizzled source chunk
  const int vrow = tid >> 4;          // V: 32 rows per round
  const int vcol = ((tid & 15) * 8) ^ ((vrow & 7) * 8);  // swizzled source chunk

  for (int phase = 0; phase < 2; ++phase) {
    const int qt = phase == 0 ? (15 - pair) : pair;

    // wave's 16 q-rows: A-frag m = col (direct global, once per phase)
    bf16x8 qf[2];
    {
      const long t = (long)qt * 128 + w * 16 + col;
      const unsigned short* qp = Qb + (bbase + t) * EMB + hoff;
#pragma unroll
      for (int ks = 0; ks < 2; ++ks) qf[ks] = *(const bf16x8*)(qp + ks * 32 + quad * 8);
    }

    float li[4] = {0.f, 0.f, 0.f, 0.f};
    f32x4 o[4];
#pragma unroll
    for (int dt = 0; dt < 4; ++dt) o[dt] = (f32x4){0.f, 0.f, 0.f, 0.f};

    for (int kv = 0; kv <= qt; ++kv) {
      __syncthreads();  // protect sK/sV against previous iteration's readers
      // stage K tile [128][64h] and V^T tile [64][128h], coalesced 16B/lane, swizzled src
#pragma unroll
      for (int it = 0; it < 2; ++it) {
        const unsigned short* gk = Kb + (bbase + (long)kv * 128 + it * 64 + krow) * EMB + hoff + kcol;
        __builtin_amdgcn_global_load_lds((const __attribute__((address_space(1))) void*)gk,
                                         (__attribute__((address_space(3))) void*)&sK[it * 4096 + tid * 8],
                                         16, 0, 0);
        const unsigned short* gv = vbase + ((long)(it * 32 + vrow) << 11) + kv * 128 + vcol;
        __builtin_amdgcn_global_load_lds((const __attribute__((address_space(1))) void*)gv,
                                         (__attribute__((address_space(3))) void*)&sV[it * 4096 + tid * 8],
                                         16, 0, 0);
      }
      __syncthreads();

      // S = Q K^T  (K b-frags from LDS, swizzled)
      f32x4 sa[8];
#pragma unroll
      for (int nt = 0; nt < 8; ++nt) sa[nt] = (f32x4){0.f, 0.f, 0.f, 0.f};
#pragma unroll
      for (int ks = 0; ks < 2; ++ks) {
        const int off = (ks * 32 + quad * 8) ^ cx;
#pragma unroll
        for (int nt = 0; nt < 8; ++nt) {
          bf16x8 kf = *(const bf16x8*)&sK[(nt * 16 + col) * 64 + off];
          sa[nt] = MFMA16(qf[ks], kf, sa[nt]);
        }
      }

      if (kv == qt) {  // causal mask, diagonal tile only
#pragma unroll
        for (int nt = 0; nt < 8; ++nt)
#pragma unroll
          for (int r = 0; r < 4; ++r) {
            const int trel = w * 16 + quad * 4 + r;
            const int srel = nt * 16 + col;
            if (srel > trel) sa[nt][r] = -INFINITY;
          }
      }

      // max-free softmax: p = exp2(s*sc2); per-lane partial row sums; P -> wave-private LDS
#pragma unroll
      for (int nt = 0; nt < 8; ++nt)
#pragma unroll
        for (int r = 0; r < 4; ++r) {
          const float p = exp2f(sa[nt][r] * sc2);
          li[r] += p;
          sP[w][(quad * 4 + r) * PSTR + nt * 16 + col] = f2bf(p);
        }

      // O += P V   (P A-frags via per-wave LDS; V^T b-frags from LDS, swizzled)
#pragma unroll
      for (int ks = 0; ks < 4; ++ks) {
        bf16x8 pa = *(const bf16x8*)&sP[w][col * PSTR + ks * 32 + quad * 8];
        const int voff = (ks * 32 + quad * 8) ^ cx;
#pragma unroll
        for (int dt = 0; dt < 4; ++dt) {
          bf16x8 vf = *(const bf16x8*)&sV[(dt * 16 + col) * 128 + voff];
          o[dt] = MFMA16(pa, vf, o[dt]);
        }
      }
    }

    // epilogue: cross-lane row-sum reduce (16-lane groups)
#pragma unroll
    for (int d = 1; d < 16; d <<= 1)
#pragma unroll
      for (int r = 0; r < 4; ++r) li[r] += __shfl_xor(li[r], d);

    // stage this wave's 16 output rows (bf16) in sP[w] at stride 72 (wave-private;
    // compiler orders the ds_write->ds_read dependency with lgkmcnt)
#pragma unroll
    for (int r = 0; r < 4; ++r) {
      const float inv = 1.0f / li[r];
#pragma unroll
      for (int dt = 0; dt < 4; ++dt)
        sP[w][(quad * 4 + r) * 72 + dt * 16 + col] = f2bf(o[dt][r] * inv);
    }
    // coalesced store: lane covers chunk (lane&7) of row (lane>>3) (+8 second pass);
    // 8 lanes x 16B = 128B fully-written per row, 8 rows per instruction.
#pragma unroll
    for (int p = 0; p < 2; ++p) {
      const int rr = (lane >> 3) + p * 8;
      bf16x8 vrow = *(const bf16x8*)&sP[w][rr * 72 + (lane & 7) * 8];
      const long t = (long)qt * 128 + w * 16 + rr;
      *(bf16x8*)(Ctx + (bbase + t) * EMB + hoff + (lane & 7) * 8) = vrow;
    }
  }
}

// ---------------------------------------------------------------- host orchestration
extern "C" void kernel_launch(void* const* d_in, const int* in_sizes, int n_in,
                              void* d_out, int out_size, void* d_ws, size_t ws_size,
                              hipStream_t stream) {
  const float* x    = (const float*)d_in[0];
  const float* Wq_w = (const float*)d_in[1];
  const float* Wq_b = (const float*)d_in[2];
  const float* Wk_w = (const float*)d_in[3];
  const float* Wk_b = (const float*)d_in[4];
  const float* Wv_w = (const float*)d_in[5];
  const float* Wv_b = (const float*)d_in[6];
  const float* Wo_w = (const float*)d_in[7];
  const float* Wo_b = (const float*)d_in[8];
  const float* l1_w = (const float*)d_in[9];
  const float* l1_b = (const float*)d_in[10];
  const float* l2_w = (const float*)d_in[11];
  const float* l2_b = (const float*)d_in[12];
  const float* n1s  = (const float*)d_in[13];
  const float* n1h  = (const float*)d_in[14];
  const float* n2s  = (const float*)d_in[15];
  const float* n2h  = (const float*)d_in[16];

  char* ws = (char*)d_ws;
  const size_t MB = (size_t)1 << 20;
  unsigned short* wqkv = (unsigned short*)(ws + 0 * MB);  // 6 MB packed [3072][1024]
  unsigned short* wo = (unsigned short*)(ws + 6 * MB);    // 2 MB
  unsigned short* l1 = (unsigned short*)(ws + 8 * MB);    // 8 MB
  unsigned short* l2 = (unsigned short*)(ws + 16 * MB);   // 8 MB
  unsigned short* hb = (unsigned short*)(ws + 24 * MB);   // 16 MB (h1 then h2)
  unsigned short* qb = (unsigned short*)(ws + 40 * MB);   // 16 MB ┐
  unsigned short* kb = (unsigned short*)(ws + 56 * MB);   // 16 MB │ overlaid later by
  unsigned short* vb = (unsigned short*)(ws + 72 * MB);   // 16 MB │ 64 MB FFN buffer
  unsigned short* cb = (unsigned short*)(ws + 88 * MB);   // 16 MB ┘
  unsigned short* gb = qb;                                // 64 MB FFN intermediate
  float* x2 = (float*)(ws + 104 * MB);                    // 32 MB
  float* rs = (float*)(ws + 136 * MB);
  float* rq = (float*)(ws + 136 * MB + 64 * 1024);
  float* st = (float*)(ws + 136 * MB + 128 * 1024);
  float* bqkv = (float*)(ws + 136 * MB + 192 * 1024);     // 12 KB
  float* rs2 = (float*)(ws + 136 * MB + 256 * 1024);
  float* rq2 = (float*)(ws + 136 * MB + 320 * 1024);

  // fused setup: weight cvt + bias pack + LN1 row sums + zero LN2 accumulators
  prep<<<20508, 256, 0, stream>>>(Wq_w, Wk_w, Wv_w, Wo_w, l1_w, l2_w, wqkv, wo, l1, l2,
                                  Wq_b, Wk_b, Wv_b, bqkv, x, rs, rq, rs2, rq2);

  // LN1 finish
  finalize_stats<<<1, 256, 0, stream>>>(rs, rq, st);
  ln_apply<<<SEQB, 256, 0, stream>>>(x, rs, st, n1s, n1h, hb);

  // fused QKV projection (V written pre-transposed as [b*16+h][d][t])
  dim3 g1(EMB / 128, SEQB / 128);
  gemm_bt<4><<<dim3(3 * EMB / 128, SEQB / 128), 256, 0, stream>>>(
      hb, wqkv, bqkv, nullptr, qb, kb, vb, SEQB, 3 * EMB, EMB);

  // causal attention (XCD-local, LDS-staged K/V, swizzled, coalesced epilogue)
  attn10<<<dim3(BATCH * HEADS, 8), 512, 0, stream>>>(qb, kb, vb, cb);

  // output projection + residual -> x2 (fp32), fused LN2 row sums (EPI 3)
  gemm_bt<3><<<g1, 256, 0, stream>>>(cb, wo, Wo_b, x, (void*)x2,
                                     (unsigned short*)rs2, (unsigned short*)rq2, SEQB, EMB, EMB);

  // LN2 finish (row_reduce eliminated -- accumulated in Wo epilogue)
  finalize_stats<<<1, 256, 0, stream>>>(rs2, rq2, st);
  ln_apply<<<SEQB, 256, 0, stream>>>(x2, rs2, st, n2s, n2h, hb);

  // FFN
  gemm_bt<2><<<dim3(DFF / 128, SEQB / 128), 256, 0, stream>>>(hb, l1, l1_b, nullptr, gb, nullptr, nullptr, SEQB, DFF, EMB);
  gemm_bt<1><<<g1, 256, 0, stream>>>(gb, l2, l2_b, x2, d_out, nullptr, nullptr, SEQB, EMB, DFF);
}

// Round 8
// 524.626 us; speedup vs baseline: 1.0306x; 1.0306x over previous
//
#include <hip/hip_runtime.h>
#include <cstdint>

#define EMB   1024
#define HEADS 16
#define HDIM  64
#define DFF   4096
#define TLEN  2048
#define BATCH 4
#define SEQB  8192   // BATCH*TLEN token rows
#define EPSLN 1e-5f

typedef __attribute__((ext_vector_type(8))) short bf16x8;
typedef __attribute__((ext_vector_type(4))) float f32x4;

#define MFMA16(a, b, c) __builtin_amdgcn_mfma_f32_16x16x32_bf16((a), (b), (c), 0, 0, 0)

__device__ __forceinline__ unsigned short f2bf(float f) {
  unsigned int u = __float_as_uint(f);
  u += 0x7fffu + ((u >> 16) & 1u);   // round-to-nearest-even
  return (unsigned short)(u >> 16);
}

// HW packed f32->bf16 (RNE, bit-identical to f2bf): 1 instr per 2 values vs 10.
// No builtin on gfx950 (T12) -> inline asm.
__device__ __forceinline__ unsigned int cvt_pk_bf16(float a, float b) {
  unsigned int r;
  asm("v_cvt_pk_bf16_f32 %0, %1, %2" : "=v"(r) : "v"(a), "v"(b));
  return r;
}

// tanh-form GELU: 0.5x(1+tanh(.79788456(x+.044715x^3))) = x*t/(t+1),
// t = exp2(2.885390082*(.79788456x+.035677408x^3)); |err| ~3e-4, cheap (no erf).
__device__ __forceinline__ float gelu_f(float x) {
  float x2 = x * x;
  float inner = x * (0.79788456f + 0.035677408f * x2);
  float t = exp2f(2.885390082f * inner);
  return x * t / (t + 1.0f);
}

// ---------------------------------------------------------------- prep: fused one-shot setup
// blocks [0,12288): weight fp32->bf16 cvt (wq,wk,wv -> packed wqkv; wo; l1; l2)
// blocks [12288,20480): LN1 row sums over x (row = bid-12288)
// blocks [20480,20492): pack3 qkv bias
// blocks [20492,20508): zero rs2/rq2 (LN2 accumulators fed by Wo epilogue atomics)
__global__ __launch_bounds__(256) void prep(const float* __restrict__ wq, const float* __restrict__ wk,
                                            const float* __restrict__ wv, const float* __restrict__ wom,
                                            const float* __restrict__ l1w, const float* __restrict__ l2w,
                                            unsigned short* __restrict__ wqkv, unsigned short* __restrict__ wo,
                                            unsigned short* __restrict__ l1, unsigned short* __restrict__ l2,
                                            const float* __restrict__ bq, const float* __restrict__ bk,
                                            const float* __restrict__ bv, float* __restrict__ bqkv,
                                            const float* __restrict__ X, float* __restrict__ rs,
                                            float* __restrict__ rq, float* __restrict__ rs2,
                                            float* __restrict__ rq2) {
  __shared__ float ss[4], sq[4];
  const int bid = blockIdx.x;
  const int tid = threadIdx.x;
  if (bid < 12288) {                       // ---- weight cvt (exact-range, no bounds check)
    const float* src;
    unsigned short* dst;
    int off;
    if (bid < 1024)      { src = wq;  dst = wqkv;               off = bid; }
    else if (bid < 2048) { src = wk;  dst = wqkv + (1 << 20);   off = bid - 1024; }
    else if (bid < 3072) { src = wv;  dst = wqkv + (2 << 20);   off = bid - 2048; }
    else if (bid < 4096) { src = wom; dst = wo;                 off = bid - 3072; }
    else if (bid < 8192) { src = l1w; dst = l1;                 off = bid - 4096; }
    else                 { src = l2w; dst = l2;                 off = bid - 8192; }
    const int i = off * 256 + tid;
    float4 v = ((const float4*)src)[i];
    ushort4 o;
    o.x = f2bf(v.x); o.y = f2bf(v.y); o.z = f2bf(v.z); o.w = f2bf(v.w);
    ((ushort4*)dst)[i] = o;
  } else if (bid < 20480) {                // ---- LN1 row reduce
    const int row = bid - 12288;
    float4 v = ((const float4*)(X + (long)row * EMB))[tid];
    float s = v.x + v.y + v.z + v.w;
    float q = v.x * v.x + v.y * v.y + v.z * v.z + v.w * v.w;
#pragma unroll
    for (int d = 1; d < 64; d <<= 1) { s += __shfl_xor(s, d); q += __shfl_xor(q, d); }
    const int wv_ = tid >> 6;
    if ((tid & 63) == 0) { ss[wv_] = s; sq[wv_] = q; }
    __syncthreads();
    if (tid == 0) {
      rs[row] = ss[0] + ss[1] + ss[2] + ss[3];
      rq[row] = sq[0] + sq[1] + sq[2] + sq[3];
    }
  } else if (bid < 20492) {                // ---- pack3 qkv bias
    const int i = (bid - 20480) * 256 + tid;  // 0..3071
    bqkv[i] = i < 1024 ? bq[i] : (i < 2048 ? bk[i - 1024] : bv[i - 2048]);
  } else {                                 // ---- zero rs2/rq2 (4096 float4 total)
    const int i = (bid - 20492) * 256 + tid;  // 0..4095
    if (i < 2048) ((float4*)rs2)[i] = (float4){0.f, 0.f, 0.f, 0.f};
    else          ((float4*)rq2)[i - 2048] = (float4){0.f, 0.f, 0.f, 0.f};
  }
}

// ---------------------------------------------------------------- LN pass 2: global var
__global__ __launch_bounds__(256) void finalize_stats(const float* __restrict__ rs,
                                                      const float* __restrict__ rq,
                                                      float* __restrict__ stats) {
  const int tid = threadIdx.x;
  float s = 0.f, q = 0.f;
  for (int i = tid; i < SEQB; i += 256) { s += rs[i]; q += rq[i]; }
#pragma unroll
  for (int d = 1; d < 64; d <<= 1) { s += __shfl_xor(s, d); q += __shfl_xor(q, d); }
  __shared__ float ss[4], sq[4];
  const int wv = tid >> 6;
  if ((tid & 63) == 0) { ss[wv] = s; sq[wv] = q; }
  __syncthreads();
  if (tid == 0) {
    double n = (double)SEQB * (double)EMB;
    double mean = (double)(ss[0] + ss[1] + ss[2] + ss[3]) / n;
    double var = (double)(sq[0] + sq[1] + sq[2] + sq[3]) / n - mean * mean;
    stats[0] = (float)(1.0 / var);
  }
}

// ---------------------------------------------------------------- LN apply + cast bf16
__global__ __launch_bounds__(256) void ln_apply(const float* __restrict__ X,
                                                const float* __restrict__ rs,
                                                const float* __restrict__ stats,
                                                const float* __restrict__ scale,
                                                const float* __restrict__ shift,
                                                unsigned short* __restrict__ H) {
  const long i = (long)blockIdx.x * 256 + threadIdx.x;  // float4 index
  const long idx = i * 4;
  const int row = (int)(idx >> 10);
  const int c = (int)(idx & 1023);
  const float mean = rs[row] * (1.0f / EMB);
  const float iv = stats[0];
  float4 x = ((const float4*)X)[i];
  float4 sc = *(const float4*)(scale + c);
  float4 sh = *(const float4*)(shift + c);
  ushort4 o;
  o.x = f2bf(((x.x - mean) * iv + EPSLN) * sc.x + sh.x);
  o.y = f2bf(((x.y - mean) * iv + EPSLN) * sc.y + sh.y);
  o.z = f2bf(((x.z - mean) * iv + EPSLN) * sc.z + sh.z);
  o.w = f2bf(((x.w - mean) * iv + EPSLN) * sc.w + sh.w);
  ((ushort4*)H)[i] = o;
}

// ---------------------------------------------------------------- GEMM: C = A (bf16 [M][K]) x W^T (bf16 [N][K]) + bias
// Harness-proven 128x128 structure: 256 thr, 32 KiB LDS, XOR-swizzled
// (SQ_LDS_BANK_CONFLICT=0 measured), T1 XCD remap. K-loop untouched since r1.
// bf16 epilogues now use v_cvt_pk_bf16_f32 (1 instr / 2 values, RNE, bit-identical).
// EPI 0: bf16 ; EPI 1: fp32 (+residual) ; EPI 2: tanh-GELU -> bf16
// EPI 3: fp32 (+residual) + per-row sum/sumsq atomics into kout/vout (as float*)
// EPI 4: fused QKV: seg=bn>>10 (block-uniform): 0 -> q, 1 -> k, 2 -> v transposed [b*1024+d][t]
template <int EPI>
__global__ __launch_bounds__(256) void gemm_bt(const unsigned short* __restrict__ A,
                                               const unsigned short* __restrict__ W,
                                               const float* __restrict__ bias,
                                               const float* __restrict__ resid,
                                               void* __restrict__ Cout,
                                               unsigned short* __restrict__ kout,
                                               unsigned short* __restrict__ vout,
                                               int M, int N, int K) {
  __shared__ unsigned short sA[128 * 64];
  __shared__ unsigned short sB[128 * 64];
  const int tid = threadIdx.x;
  const int lane = tid & 63;
  const int wave = tid >> 6;
  const int wm = (wave >> 1) * 64, wn = (wave & 1) * 64;
  const int col = lane & 15, quad = lane >> 4;
  const int cx = (col & 7) * 8;            // read-side xor key (halves)

  // T1: XCD-aware bijective block remap (8 XCDs on MI355X)
  const int gx = (int)gridDim.x, gy = (int)gridDim.y;
  const int nwg = gx * gy;
  int bid = (int)blockIdx.y * gx + (int)blockIdx.x;
  if ((nwg & 7) == 0) bid = (bid & 7) * (nwg >> 3) + (bid >> 3);
  const int bx = bid % gx;
  const int by = bid / gx;
  const long bm = (long)by * 128, bn = (long)bx * 128;

  f32x4 acc[4][4];
#pragma unroll
  for (int i = 0; i < 4; ++i)
#pragma unroll
    for (int j = 0; j < 4; ++j) acc[i][j] = (f32x4){0.f, 0.f, 0.f, 0.f};

  const int r0 = tid >> 3;
  const int kg = (tid & 7) * 8;
  const int rx = (r0 & 7) * 8;             // staging-side xor key (halves)
  const int kgx = kg ^ rx;                 // swizzled source column chunk

  for (int k0 = 0; k0 < K; k0 += 64) {
#pragma unroll
    for (int it = 0; it < 4; ++it) {
      const int r = it * 32 + r0;
      const unsigned short* ga = A + (bm + r) * K + k0 + kgx;
      const unsigned short* gb = W + (bn + r) * K + k0 + kgx;
      __builtin_amdgcn_global_load_lds((const __attribute__((address_space(1))) void*)ga,
                                       (__attribute__((address_space(3))) void*)&sA[r * 64 + kg],
                                       16, 0, 0);
      __builtin_amdgcn_global_load_lds((const __attribute__((address_space(1))) void*)gb,
                                       (__attribute__((address_space(3))) void*)&sB[r * 64 + kg],
                                       16, 0, 0);
    }
    __syncthreads();
#pragma unroll
    for (int ks = 0; ks < 2; ++ks) {
      const int off = (ks * 32 + quad * 8) ^ cx;
      bf16x8 af[4], bfr[4];
#pragma unroll
      for (int mt = 0; mt < 4; ++mt)
        af[mt] = *(const bf16x8*)&sA[(wm + mt * 16 + col) * 64 + off];
#pragma unroll
      for (int nt = 0; nt < 4; ++nt)
        bfr[nt] = *(const bf16x8*)&sB[(wn + nt * 16 + col) * 64 + off];
#pragma unroll
      for (int mt = 0; mt < 4; ++mt)
#pragma unroll
        for (int nt = 0; nt < 4; ++nt) acc[mt][nt] = MFMA16(af[mt], bfr[nt], acc[mt][nt]);
    }
    __syncthreads();
  }

#pragma unroll
  for (int mt = 0; mt < 4; ++mt) {
    const long row0 = bm + wm + mt * 16 + quad * 4;
    if (EPI == 3) {
      float s4[4] = {0.f, 0.f, 0.f, 0.f}, q4[4] = {0.f, 0.f, 0.f, 0.f};
#pragma unroll
      for (int nt = 0; nt < 4; ++nt) {
        const long c = bn + wn + nt * 16 + col;
        const float bv = bias[c];
#pragma unroll
        for (int r = 0; r < 4; ++r) {
          const long row = row0 + r;
          const float v = acc[mt][nt][r] + bv + resid[row * N + c];
          ((float*)Cout)[row * N + c] = v;
          s4[r] += v;
          q4[r] += v * v;
        }
      }
#pragma unroll
      for (int r = 0; r < 4; ++r)
#pragma unroll
        for (int d = 1; d < 16; d <<= 1) {
          s4[r] += __shfl_xor(s4[r], d);
          q4[r] += __shfl_xor(q4[r], d);
        }
      if (col == 0) {
#pragma unroll
        for (int r = 0; r < 4; ++r) {
          atomicAdd((float*)kout + row0 + r, s4[r]);
          atomicAdd((float*)vout + row0 + r, q4[r]);
        }
      }
    } else {
#pragma unroll
      for (int nt = 0; nt < 4; ++nt) {
        const long c = bn + wn + nt * 16 + col;
        const float bv = bias[c];
        if (EPI == 4) {
          const int seg = (int)(bn >> 10);  // block-uniform
          const unsigned int pk0 = cvt_pk_bf16(acc[mt][nt][0] + bv, acc[mt][nt][1] + bv);
          const unsigned int pk1 = cvt_pk_bf16(acc[mt][nt][2] + bv, acc[mt][nt][3] + bv);
          if (seg == 2) {
            ushort4 o;
            o.x = (unsigned short)pk0; o.y = (unsigned short)(pk0 >> 16);
            o.z = (unsigned short)pk1; o.w = (unsigned short)(pk1 >> 16);
            const long bidx = row0 >> 11;
            const long t0 = row0 & 2047;
            *(ushort4*)(vout + (((bidx * 1024 + (c & 1023)) << 11) + t0)) = o;
          } else {
            unsigned short* dst = seg == 0 ? (unsigned short*)Cout : kout;
            const int cc = (int)(c & 1023);
            dst[(row0 + 0) * 1024 + cc] = (unsigned short)pk0;
            dst[(row0 + 1) * 1024 + cc] = (unsigned short)(pk0 >> 16);
            dst[(row0 + 2) * 1024 + cc] = (unsigned short)pk1;
            dst[(row0 + 3) * 1024 + cc] = (unsigned short)(pk1 >> 16);
          }
        } else if (EPI == 2) {
          const unsigned int pk0 = cvt_pk_bf16(gelu_f(acc[mt][nt][0] + bv), gelu_f(acc[mt][nt][1] + bv));
          const unsigned int pk1 = cvt_pk_bf16(gelu_f(acc[mt][nt][2] + bv), gelu_f(acc[mt][nt][3] + bv));
          ((unsigned short*)Cout)[(row0 + 0) * N + c] = (unsigned short)pk0;
          ((unsigned short*)Cout)[(row0 + 1) * N + c] = (unsigned short)(pk0 >> 16);
          ((unsigned short*)Cout)[(row0 + 2) * N + c] = (unsigned short)pk1;
          ((unsigned short*)Cout)[(row0 + 3) * N + c] = (unsigned short)(pk1 >> 16);
        } else {
#pragma unroll
          for (int r = 0; r < 4; ++r) {
            const long row = row0 + r;
            float v = acc[mt][nt][r] + bv;
            if (EPI == 0) {
              ((unsigned short*)Cout)[row * N + c] = f2bf(v);
            } else {  // EPI == 1
              ((float*)Cout)[row * N + c] = v + resid[row * N + c];
            }
          }
        }
      }
    }
  }
}

// ---------------------------------------------------------------- causal flash attention v11
// = r6-proven attn10 (global_load_lds staging, swizzled LDS, coalesced LDS-staged
// epilogue) + v_cvt_pk_bf16_f32 softmax/epilogue conversion: the hand-rolled 5-op
// f2bf was ~320 cy/kv-iter/wave of pure VALU (32 conversions); cvt_pk is 1 instr
// per 2 values, RNE, bit-identical. Attacks the measured VALUBusy=43% vs
// MfmaUtil=12.6% imbalance.
#define PSTR 136
__global__ __launch_bounds__(512, 4) void attn11(const unsigned short* __restrict__ Qb,
                                                 const unsigned short* __restrict__ Kb,
                                                 const unsigned short* __restrict__ vT,
                                                 unsigned short* __restrict__ Ctx) {
  __shared__ unsigned short sK[128 * 64];   // [t_local][d] 16KB, xor-swizzled
  __shared__ unsigned short sV[64 * 128];   // [d][s_local] 16KB, xor-swizzled
  __shared__ unsigned short sP[8][16 * PSTR];
  const int bh = blockIdx.x;                   // b*16+h
  const int pair = blockIdx.y;                 // 0..7
  const int b = bh >> 4, h = bh & 15;
  const int tid = threadIdx.x, lane = tid & 63, w = tid >> 6;
  const int col = lane & 15, quad = lane >> 4;
  const int cx = (col & 7) * 8;                // read-side xor key
  const long bbase = (long)b * TLEN;
  const long hoff = (long)h * HDIM;
  const unsigned short* vbase = vT + (((long)b * 16 + h) * HDIM << 11);
  const float sc2 = 0.125f * 1.44269504088896340736f;  // (1/sqrt(64)) * log2(e)

  // staging decomposition (block-wide, 512 threads x 16B):
  const int krow = tid >> 3;          // K: 64 rows per round
  const int kcol = ((tid & 7) * 8) ^ ((krow & 7) * 8);   // swizzled source chunk
  const int vrow = tid >> 4;          // V: 32 rows per round
  const int vcol = ((tid & 15) * 8) ^ ((vrow & 7) * 8);  // swizzled source chunk

  for (int phase = 0; phase < 2; ++phase) {
    const int qt = phase == 0 ? (15 - pair) : pair;

    // wave's 16 q-rows: A-frag m = col (direct global, once per phase)
    bf16x8 qf[2];
    {
      const long t = (long)qt * 128 + w * 16 + col;
      const unsigned short* qp = Qb + (bbase + t) * EMB + hoff;
#pragma unroll
      for (int ks = 0; ks < 2; ++ks) qf[ks] = *(const bf16x8*)(qp + ks * 32 + quad * 8);
    }

    float li[4] = {0.f, 0.f, 0.f, 0.f};
    f32x4 o[4];
#pragma unroll
    for (int dt = 0; dt < 4; ++dt) o[dt] = (f32x4){0.f, 0.f, 0.f, 0.f};

    for (int kv = 0; kv <= qt; ++kv) {
      __syncthreads();  // protect sK/sV against previous iteration's readers
      // stage K tile [128][64h] and V^T tile [64][128h], coalesced 16B/lane, swizzled src
#pragma unroll
      for (int it = 0; it < 2; ++it) {
        const unsigned short* gk = Kb + (bbase + (long)kv * 128 + it * 64 + krow) * EMB + hoff + kcol;
        __builtin_amdgcn_global_load_lds((const __attribute__((address_space(1))) void*)gk,
                                         (__attribute__((address_space(3))) void*)&sK[it * 4096 + tid * 8],
                                         16, 0, 0);
        const unsigned short* gv = vbase + ((long)(it * 32 + vrow) << 11) + kv * 128 + vcol;
        __builtin_amdgcn_global_load_lds((const __attribute__((address_space(1))) void*)gv,
                                         (__attribute__((address_space(3))) void*)&sV[it * 4096 + tid * 8],
                                         16, 0, 0);
      }
      __syncthreads();

      // S = Q K^T  (K b-frags from LDS, swizzled)
      f32x4 sa[8];
#pragma unroll
      for (int nt = 0; nt < 8; ++nt) sa[nt] = (f32x4){0.f, 0.f, 0.f, 0.f};
#pragma unroll
      for (int ks = 0; ks < 2; ++ks) {
        const int off = (ks * 32 + quad * 8) ^ cx;
#pragma unroll
        for (int nt = 0; nt < 8; ++nt) {
          bf16x8 kf = *(const bf16x8*)&sK[(nt * 16 + col) * 64 + off];
          sa[nt] = MFMA16(qf[ks], kf, sa[nt]);
        }
      }

      if (kv == qt) {  // causal mask, diagonal tile only
#pragma unroll
        for (int nt = 0; nt < 8; ++nt)
#pragma unroll
          for (int r = 0; r < 4; ++r) {
            const int trel = w * 16 + quad * 4 + r;
            const int srel = nt * 16 + col;
            if (srel > trel) sa[nt][r] = -INFINITY;
          }
      }

      // max-free softmax: p = exp2(s*sc2); per-lane partial row sums;
      // P -> wave-private LDS via packed HW cvt (1 instr / 2 values)
#pragma unroll
      for (int nt = 0; nt < 8; ++nt)
#pragma unroll
        for (int r = 0; r < 4; r += 2) {
          const float p0 = exp2f(sa[nt][r] * sc2);
          const float p1 = exp2f(sa[nt][r + 1] * sc2);
          li[r] += p0;
          li[r + 1] += p1;
          const unsigned int pk = cvt_pk_bf16(p0, p1);
          sP[w][(quad * 4 + r) * PSTR + nt * 16 + col] = (unsigned short)pk;
          sP[w][(quad * 4 + r + 1) * PSTR + nt * 16 + col] = (unsigned short)(pk >> 16);
        }

      // O += P V   (P A-frags via per-wave LDS; V^T b-frags from LDS, swizzled)
#pragma unroll
      for (int ks = 0; ks < 4; ++ks) {
        bf16x8 pa = *(const bf16x8*)&sP[w][col * PSTR + ks * 32 + quad * 8];
        const int voff = (ks * 32 + quad * 8) ^ cx;
#pragma unroll
        for (int dt = 0; dt < 4; ++dt) {
          bf16x8 vf = *(const bf16x8*)&sV[(dt * 16 + col) * 128 + voff];
          o[dt] = MFMA16(pa, vf, o[dt]);
        }
      }
    }

    // epilogue: cross-lane row-sum reduce (16-lane groups)
#pragma unroll
    for (int d = 1; d < 16; d <<= 1)
#pragma unroll
      for (int r = 0; r < 4; ++r) li[r] += __shfl_xor(li[r], d);

    // stage this wave's 16 output rows (bf16) in sP[w] at stride 72 (wave-private;
    // compiler orders the ds_write->ds_read dependency with lgkmcnt)
#pragma unroll
    for (int r = 0; r < 4; ++r) {
      const float inv = 1.0f / li[r];
#pragma unroll
      for (int dt = 0; dt < 4; dt += 2) {
        const unsigned int pk = cvt_pk_bf16(o[dt][r] * inv, o[dt + 1][r] * inv);
        sP[w][(quad * 4 + r) * 72 + dt * 16 + col] = (unsigned short)pk;
        sP[w][(quad * 4 + r) * 72 + (dt + 1) * 16 + col] = (unsigned short)(pk >> 16);
      }
    }
    // coalesced store: lane covers chunk (lane&7) of row (lane>>3) (+8 second pass);
    // 8 lanes x 16B = 128B fully-written per row, 8 rows per instruction.
#pragma unroll
    for (int p = 0; p < 2; ++p) {
      const int rr = (lane >> 3) + p * 8;
      bf16x8 vrow = *(const bf16x8*)&sP[w][rr * 72 + (lane & 7) * 8];
      const long t = (long)qt * 128 + w * 16 + rr;
      *(bf16x8*)(Ctx + (bbase + t) * EMB + hoff + (lane & 7) * 8) = vrow;
    }
  }
}

// ---------------------------------------------------------------- host orchestration
extern "C" void kernel_launch(void* const* d_in, const int* in_sizes, int n_in,
                              void* d_out, int out_size, void* d_ws, size_t ws_size,
                              hipStream_t stream) {
  const float* x    = (const float*)d_in[0];
  const float* Wq_w = (const float*)d_in[1];
  const float* Wq_b = (const float*)d_in[2];
  const float* Wk_w = (const float*)d_in[3];
  const float* Wk_b = (const float*)d_in[4];
  const float* Wv_w = (const float*)d_in[5];
  const float* Wv_b = (const float*)d_in[6];
  const float* Wo_w = (const float*)d_in[7];
  const float* Wo_b = (const float*)d_in[8];
  const float* l1_w = (const float*)d_in[9];
  const float* l1_b = (const float*)d_in[10];
  const float* l2_w = (const float*)d_in[11];
  const float* l2_b = (const float*)d_in[12];
  const float* n1s  = (const float*)d_in[13];
  const float* n1h  = (const float*)d_in[14];
  const float* n2s  = (const float*)d_in[15];
  const float* n2h  = (const float*)d_in[16];

  char* ws = (char*)d_ws;
  const size_t MB = (size_t)1 << 20;
  unsigned short* wqkv = (unsigned short*)(ws + 0 * MB);  // 6 MB packed [3072][1024]
  unsigned short* wo = (unsigned short*)(ws + 6 * MB);    // 2 MB
  unsigned short* l1 = (unsigned short*)(ws + 8 * MB);    // 8 MB
  unsigned short* l2 = (unsigned short*)(ws + 16 * MB);   // 8 MB
  unsigned short* hb = (unsigned short*)(ws + 24 * MB);   // 16 MB (h1 then h2)
  unsigned short* qb = (unsigned short*)(ws + 40 * MB);   // 16 MB ┐
  unsigned short* kb = (unsigned short*)(ws + 56 * MB);   // 16 MB │ overlaid later by
  unsigned short* vb = (unsigned short*)(ws + 72 * MB);   // 16 MB │ 64 MB FFN buffer
  unsigned short* cb = (unsigned short*)(ws + 88 * MB);   // 16 MB ┘
  unsigned short* gb = qb;                                // 64 MB FFN intermediate
  float* x2 = (float*)(ws + 104 * MB);                    // 32 MB
  float* rs = (float*)(ws + 136 * MB);
  float* rq = (float*)(ws + 136 * MB + 64 * 1024);
  float* st = (float*)(ws + 136 * MB + 128 * 1024);
  float* bqkv = (float*)(ws + 136 * MB + 192 * 1024);     // 12 KB
  float* rs2 = (float*)(ws + 136 * MB + 256 * 1024);
  float* rq2 = (float*)(ws + 136 * MB + 320 * 1024);

  // fused setup: weight cvt + bias pack + LN1 row sums + zero LN2 accumulators
  prep<<<20508, 256, 0, stream>>>(Wq_w, Wk_w, Wv_w, Wo_w, l1_w, l2_w, wqkv, wo, l1, l2,
                                  Wq_b, Wk_b, Wv_b, bqkv, x, rs, rq, rs2, rq2);

  // LN1 finish
  finalize_stats<<<1, 256, 0, stream>>>(rs, rq, st);
  ln_apply<<<SEQB, 256, 0, stream>>>(x, rs, st, n1s, n1h, hb);

  // fused QKV projection (V written pre-transposed as [b*16+h][d][t])
  dim3 g1(EMB / 128, SEQB / 128);
  gemm_bt<4><<<dim3(3 * EMB / 128, SEQB / 128), 256, 0, stream>>>(
      hb, wqkv, bqkv, nullptr, qb, kb, vb, SEQB, 3 * EMB, EMB);

  // causal attention (XCD-local, LDS-staged K/V, swizzled, packed-cvt softmax)
  attn11<<<dim3(BATCH * HEADS, 8), 512, 0, stream>>>(qb, kb, vb, cb);

  // output projection + residual -> x2 (fp32), fused LN2 row sums (EPI 3)
  gemm_bt<3><<<g1, 256, 0, stream>>>(cb, wo, Wo_b, x, (void*)x2,
                                     (unsigned short*)rs2, (unsigned short*)rq2, SEQB, EMB, EMB);

  // LN2 finish (row_reduce eliminated -- accumulated in Wo epilogue)
  finalize_stats<<<1, 256, 0, stream>>>(rs2, rq2, st);
  ln_apply<<<SEQB, 256, 0, stream>>>(x2, rs2, st, n2s, n2h, hb);

  // FFN
  gemm_bt<2><<<dim3(DFF / 128, SEQB / 128), 256, 0, stream>>>(hb, l1, l1_b, nullptr, gb, nullptr, nullptr, SEQB, DFF, EMB);
  gemm_bt<1><<<g1, 256, 0, stream>>>(gb, l2, l2_b, x2, d_out, nullptr, nullptr, SEQB, EMB, DFF);
}